// Round 1
// baseline (17732.191 us; speedup 1.0000x reference)
//
#include <hip/hip_runtime.h>
#include <math.h>

#define HDIM 256
#define BATCH 64
#define TLEN 512
#define IDIM 64

// ---------------- ws layout (float offsets) ----------------
// xg4:    [64][512][1024]  gate-interleaved (j*4+gate)   33,554,432
// yA:     [64][512][256]                                  8,388,608
// yB:     [64][512][256]                                  8,388,608
// wihT:   4 layers x [1024][256] (layer0 uses K=64)       1,048,576
// whhT4:  4 layers x [256 k][256 j][4 gate]               1,048,576
// bsum:   4 x [1024]                                          4,096
// states: h0T,c0T,h1T,c1T each [64][256]                      65,536
static const size_t OFF_XG    = 0;
static const size_t OFF_YA    = 33554432;
static const size_t OFF_YB    = OFF_YA + 8388608;
static const size_t OFF_WIHT  = OFF_YB + 8388608;
static const size_t OFF_WHHT  = OFF_WIHT + 1048576;
static const size_t OFF_BSUM  = OFF_WHHT + 1048576;
static const size_t OFF_STATE = OFF_BSUM + 4096;

__device__ __forceinline__ float sigmoidf_(float x) { return 1.f / (1.f + __expf(-x)); }

// -------- prep: weight re-layouts --------
__global__ void prep_wih(const float* __restrict__ w, float* __restrict__ wt, int K) {
    int idx = blockIdx.x * 256 + threadIdx.x;
    if (idx >= 1024 * K) return;
    int n = idx / K, k = idx - n * K;
    int j = n >> 2, g = n & 3;
    wt[idx] = w[(g * 256 + j) * K + k];
}

__global__ void prep_whh(const float* __restrict__ w, float* __restrict__ wt) {
    int idx = blockIdx.x * 256 + threadIdx.x;   // 262144 per layer
    int k = idx >> 10, r = idx & 1023;
    int j = r >> 2, g = r & 3;
    wt[idx] = w[(g * 256 + j) * 256 + k];
}

__global__ void prep_bias(const float* __restrict__ bi, const float* __restrict__ bh,
                          float* __restrict__ bs) {
    int n = blockIdx.x * 256 + threadIdx.x;     // 1024
    int j = n >> 2, g = n & 3;
    bs[n] = bi[g * 256 + j] + bh[g * 256 + j];
}

// -------- projection GEMM: out[m][n] = sum_k A[m][k]*Wt[n][k] + bsum[n] --------
// M = 32768, N = 1024. BM=BN=128, BK=16, 256 threads, 8x8 microtile.
__global__ __launch_bounds__(256) void proj_kernel(
    const float* __restrict__ A, int K, int doRelu,
    const float* __restrict__ Wt, const float* __restrict__ bsum,
    float* __restrict__ out)
{
    __shared__ float As[16][128];
    __shared__ float Bs[16][128];
    const int tid = threadIdx.x;
    const int m0 = blockIdx.x * 128;
    const int n0 = blockIdx.y * 128;
    const int tx = tid & 15, ty = tid >> 4;

    float acc[8][8];
#pragma unroll
    for (int i = 0; i < 8; ++i)
#pragma unroll
        for (int j = 0; j < 8; ++j) acc[i][j] = 0.f;

    for (int kt = 0; kt < K; kt += 16) {
#pragma unroll
        for (int l = 0; l < 2; ++l) {
            int f = tid * 2 + l;          // 0..511
            int r = f >> 2;               // 0..127
            int c = (f & 3) << 2;         // 0,4,8,12
            float4 v = *(const float4*)&A[(size_t)(m0 + r) * K + kt + c];
            if (doRelu) {
                v.x = fmaxf(v.x, 0.f); v.y = fmaxf(v.y, 0.f);
                v.z = fmaxf(v.z, 0.f); v.w = fmaxf(v.w, 0.f);
            }
            As[c + 0][r] = v.x; As[c + 1][r] = v.y; As[c + 2][r] = v.z; As[c + 3][r] = v.w;
            float4 w = *(const float4*)&Wt[(size_t)(n0 + r) * K + kt + c];
            Bs[c + 0][r] = w.x; Bs[c + 1][r] = w.y; Bs[c + 2][r] = w.z; Bs[c + 3][r] = w.w;
        }
        __syncthreads();
#pragma unroll
        for (int kk = 0; kk < 16; ++kk) {
            float a[8], bb[8];
            *(float4*)&a[0]  = *(const float4*)&As[kk][ty * 8];
            *(float4*)&a[4]  = *(const float4*)&As[kk][ty * 8 + 4];
            *(float4*)&bb[0] = *(const float4*)&Bs[kk][tx * 8];
            *(float4*)&bb[4] = *(const float4*)&Bs[kk][tx * 8 + 4];
#pragma unroll
            for (int i = 0; i < 8; ++i)
#pragma unroll
                for (int j = 0; j < 8; ++j) acc[i][j] = fmaf(a[i], bb[j], acc[i][j]);
        }
        __syncthreads();
    }

    float bsv[8];
#pragma unroll
    for (int j = 0; j < 8; ++j) bsv[j] = bsum[n0 + tx * 8 + j];
#pragma unroll
    for (int i = 0; i < 8; ++i) {
        size_t row = (size_t)(m0 + ty * 8 + i);
        float4 o1 = { acc[i][0] + bsv[0], acc[i][1] + bsv[1], acc[i][2] + bsv[2], acc[i][3] + bsv[3] };
        float4 o2 = { acc[i][4] + bsv[4], acc[i][5] + bsv[5], acc[i][6] + bsv[6], acc[i][7] + bsv[7] };
        *(float4*)&out[row * 1024 + n0 + tx * 8]     = o1;
        *(float4*)&out[row * 1024 + n0 + tx * 8 + 4] = o2;
    }
}

// -------- recurrence: one WG per 2 batch elements, 512 threads (k-split halves) --------
__global__ __launch_bounds__(512) void rec_kernel(
    const float* __restrict__ xg4,    // [64][512][1024]
    const float* __restrict__ whhT4,  // [256][256][4]
    float* __restrict__ y,            // [64][512][256]
    const float* __restrict__ h_init, const float* __restrict__ c_init,  // null -> zeros
    float* __restrict__ h_save, float* __restrict__ c_save)              // null -> skip
{
    __shared__ float hsm[2][2][HDIM];
    __shared__ float psum[8][HDIM];
    const int tid  = threadIdx.x;
    const int j    = tid & (HDIM - 1);
    const int half = tid >> 8;
    const int b0 = blockIdx.x * 2, b1 = b0 + 1;

    float c0 = 0.f, c1 = 0.f, hc0 = 0.f, hc1 = 0.f;
    if (half == 0) {
        if (h_init != nullptr) {
            hc0 = h_init[b0 * HDIM + j]; hc1 = h_init[b1 * HDIM + j];
            c0  = c_init[b0 * HDIM + j]; c1  = c_init[b1 * HDIM + j];
        }
        hsm[0][0][j] = hc0; hsm[0][1][j] = hc1;
    }
    __syncthreads();

    const float* wbase = whhT4 + (size_t)(half * 128) * 1024 + j * 4;
    int cur = 0;
    for (int t = 0; t < TLEN; ++t) {
        float ai0 = 0.f, af0 = 0.f, ag0 = 0.f, ao0 = 0.f;
        float ai1 = 0.f, af1 = 0.f, ag1 = 0.f, ao1 = 0.f;
        const float* hp0 = &hsm[cur][0][half * 128];
        const float* hp1 = &hsm[cur][1][half * 128];
#pragma unroll 8
        for (int kk = 0; kk < 128; kk += 4) {
            float4 h04 = *(const float4*)(hp0 + kk);
            float4 h14 = *(const float4*)(hp1 + kk);
            float4 w0 = *(const float4*)(wbase + (size_t)(kk + 0) * 1024);
            float4 w1 = *(const float4*)(wbase + (size_t)(kk + 1) * 1024);
            float4 w2 = *(const float4*)(wbase + (size_t)(kk + 2) * 1024);
            float4 w3 = *(const float4*)(wbase + (size_t)(kk + 3) * 1024);
            ai0 = fmaf(w0.x, h04.x, ai0); af0 = fmaf(w0.y, h04.x, af0);
            ag0 = fmaf(w0.z, h04.x, ag0); ao0 = fmaf(w0.w, h04.x, ao0);
            ai1 = fmaf(w0.x, h14.x, ai1); af1 = fmaf(w0.y, h14.x, af1);
            ag1 = fmaf(w0.z, h14.x, ag1); ao1 = fmaf(w0.w, h14.x, ao1);
            ai0 = fmaf(w1.x, h04.y, ai0); af0 = fmaf(w1.y, h04.y, af0);
            ag0 = fmaf(w1.z, h04.y, ag0); ao0 = fmaf(w1.w, h04.y, ao0);
            ai1 = fmaf(w1.x, h14.y, ai1); af1 = fmaf(w1.y, h14.y, af1);
            ag1 = fmaf(w1.z, h14.y, ag1); ao1 = fmaf(w1.w, h14.y, ao1);
            ai0 = fmaf(w2.x, h04.z, ai0); af0 = fmaf(w2.y, h04.z, af0);
            ag0 = fmaf(w2.z, h04.z, ag0); ao0 = fmaf(w2.w, h04.z, ao0);
            ai1 = fmaf(w2.x, h14.z, ai1); af1 = fmaf(w2.y, h14.z, af1);
            ag1 = fmaf(w2.z, h14.z, ag1); ao1 = fmaf(w2.w, h14.z, ao1);
            ai0 = fmaf(w3.x, h04.w, ai0); af0 = fmaf(w3.y, h04.w, af0);
            ag0 = fmaf(w3.z, h04.w, ag0); ao0 = fmaf(w3.w, h04.w, ao0);
            ai1 = fmaf(w3.x, h14.w, ai1); af1 = fmaf(w3.y, h14.w, af1);
            ag1 = fmaf(w3.z, h14.w, ag1); ao1 = fmaf(w3.w, h14.w, ao1);
        }
        if (half == 1) {
            psum[0][j] = ai0; psum[1][j] = af0; psum[2][j] = ag0; psum[3][j] = ao0;
            psum[4][j] = ai1; psum[5][j] = af1; psum[6][j] = ag1; psum[7][j] = ao1;
        }
        __syncthreads();
        if (half == 0) {
            ai0 += psum[0][j]; af0 += psum[1][j]; ag0 += psum[2][j]; ao0 += psum[3][j];
            ai1 += psum[4][j]; af1 += psum[5][j]; ag1 += psum[6][j]; ao1 += psum[7][j];
            float4 x0 = *(const float4*)&xg4[((size_t)b0 * TLEN + t) * 1024 + j * 4];
            float4 x1 = *(const float4*)&xg4[((size_t)b1 * TLEN + t) * 1024 + j * 4];
            float ig = sigmoidf_(ai0 + x0.x);
            float fg = sigmoidf_(af0 + x0.y);
            float gg = tanhf(ag0 + x0.z);
            float og = sigmoidf_(ao0 + x0.w);
            c0 = fmaf(fg, c0, ig * gg);
            hc0 = og * tanhf(c0);
            ig = sigmoidf_(ai1 + x1.x);
            fg = sigmoidf_(af1 + x1.y);
            gg = tanhf(ag1 + x1.z);
            og = sigmoidf_(ao1 + x1.w);
            c1 = fmaf(fg, c1, ig * gg);
            hc1 = og * tanhf(c1);
            y[((size_t)b0 * TLEN + t) * HDIM + j] = hc0;
            y[((size_t)b1 * TLEN + t) * HDIM + j] = hc1;
            hsm[cur ^ 1][0][j] = hc0; hsm[cur ^ 1][1][j] = hc1;
        }
        __syncthreads();
        cur ^= 1;
    }
    if (h_save != nullptr && half == 0) {
        h_save[b0 * HDIM + j] = hc0; h_save[b1 * HDIM + j] = hc1;
        c_save[b0 * HDIM + j] = c0;  c_save[b1 * HDIM + j] = c1;
    }
}

// -------- head: out[b] = dot(y3[b][511][:], lin_w) + lin_b --------
__global__ __launch_bounds__(256) void head_kernel(const float* __restrict__ y3,
    const float* __restrict__ lin_w, const float* __restrict__ lin_b, float* __restrict__ out)
{
    int b = blockIdx.x;
    int tid = threadIdx.x;
    float v = y3[((size_t)b * TLEN + (TLEN - 1)) * HDIM + tid] * lin_w[tid];
#pragma unroll
    for (int o = 32; o > 0; o >>= 1) v += __shfl_down(v, o);
    __shared__ float red[4];
    int wid = tid >> 6, lane = tid & 63;
    if (lane == 0) red[wid] = v;
    __syncthreads();
    if (tid == 0) out[b] = red[0] + red[1] + red[2] + red[3] + lin_b[0];
}

extern "C" void kernel_launch(void* const* d_in, const int* in_sizes, int n_in,
                              void* d_out, int out_size, void* d_ws, size_t ws_size,
                              hipStream_t stream) {
    const float* x = (const float*)d_in[0];
    const float* wih[4] = { (const float*)d_in[1], (const float*)d_in[5], (const float*)d_in[9],  (const float*)d_in[13] };
    const float* whh[4] = { (const float*)d_in[2], (const float*)d_in[6], (const float*)d_in[10], (const float*)d_in[14] };
    const float* bih[4] = { (const float*)d_in[3], (const float*)d_in[7], (const float*)d_in[11], (const float*)d_in[15] };
    const float* bhh[4] = { (const float*)d_in[4], (const float*)d_in[8], (const float*)d_in[12], (const float*)d_in[16] };
    const float* lin_w = (const float*)d_in[17];
    const float* lin_b = (const float*)d_in[18];
    float* ws = (float*)d_ws;

    float* xg4   = ws + OFF_XG;
    float* yA    = ws + OFF_YA;
    float* yB    = ws + OFF_YB;
    float* wihT  = ws + OFF_WIHT;
    float* whhT  = ws + OFF_WHHT;
    float* bsum  = ws + OFF_BSUM;
    float* h0T   = ws + OFF_STATE;
    float* c0T   = h0T + BATCH * HDIM;
    float* h1T   = c0T + BATCH * HDIM;
    float* c1T   = h1T + BATCH * HDIM;

    // ---- prep (every call; deterministic) ----
    for (int l = 0; l < 4; ++l) {
        int K = (l == 0) ? IDIM : HDIM;
        prep_wih<<<dim3((1024 * K + 255) / 256), 256, 0, stream>>>(wih[l], wihT + (size_t)l * 262144, K);
        prep_whh<<<dim3(1024), 256, 0, stream>>>(whh[l], whhT + (size_t)l * 262144);
        prep_bias<<<dim3(4), 256, 0, stream>>>(bih[l], bhh[l], bsum + l * 1024);
    }

    dim3 pgrid(256, 8);
    dim3 rgrid(32);

    // layer 0a: relu(x) -> xg ; recurrence from zeros; save h0T/c0T
    proj_kernel<<<pgrid, 256, 0, stream>>>(x, IDIM, 1, wihT + 0 * 262144, bsum + 0 * 1024, xg4);
    rec_kernel<<<rgrid, 512, 0, stream>>>(xg4, whhT + 0 * 262144, yA, nullptr, nullptr, h0T, c0T);

    // layer 1a: y0 -> xg ; from zeros; save h1T/c1T
    proj_kernel<<<pgrid, 256, 0, stream>>>(yA, HDIM, 0, wihT + 1 * 262144, bsum + 1 * 1024, xg4);
    rec_kernel<<<rgrid, 512, 0, stream>>>(xg4, whhT + 1 * 262144, yB, nullptr, nullptr, h1T, c1T);

    // layer 0b: relu(y1) -> xg ; init (h0T,c0T)
    proj_kernel<<<pgrid, 256, 0, stream>>>(yB, HDIM, 1, wihT + 2 * 262144, bsum + 2 * 1024, xg4);
    rec_kernel<<<rgrid, 512, 0, stream>>>(xg4, whhT + 2 * 262144, yA, h0T, c0T, nullptr, nullptr);

    // layer 1b: y2 -> xg ; init (h1T,c1T)
    proj_kernel<<<pgrid, 256, 0, stream>>>(yA, HDIM, 0, wihT + 3 * 262144, bsum + 3 * 1024, xg4);
    rec_kernel<<<rgrid, 512, 0, stream>>>(xg4, whhT + 3 * 262144, yB, h1T, c1T, nullptr, nullptr);

    // head
    head_kernel<<<dim3(BATCH), 256, 0, stream>>>(yB, lin_w, lin_b, (float*)d_out);
}